// Round 6
// baseline (792.207 us; speedup 1.0000x reference)
//
#include <hip/hip_runtime.h>
#include <math.h>

#define NV 128         // vector length (complex) = 8*8*2
#define NTRI 8256      // lower-tri entries of 128x128
#define NB 9216        // banded/16-col-padded triangle (float2 slots)
#define KAP 0.276f
#define MAXIT 20
#define TPB 512        // 8 waves; LDS ~79.9 KB -> 2 blocks/CU

__device__ __forceinline__ float2 f2(float x, float y){ return make_float2(x, y); }
__device__ __forceinline__ float2 cadd(float2 a, float2 b){ return make_float2(a.x+b.x, a.y+b.y); }
__device__ __forceinline__ float2 csub(float2 a, float2 b){ return make_float2(a.x-b.x, a.y-b.y); }
__device__ __forceinline__ float2 cmul(float2 a, float2 b){ return make_float2(a.x*b.x - a.y*b.y, a.x*b.y + a.y*b.x); }
__device__ __forceinline__ float2 cmulc(float2 a, float2 b){ // conj(a)*b
  return make_float2(a.x*b.x + a.y*b.y, a.x*b.y - a.y*b.x); }
__device__ __forceinline__ float2 cmac(float2 acc, float2 a, float2 b){ // acc += a*b
  acc.x = fmaf(a.x, b.x, fmaf(-a.y, b.y, acc.x));
  acc.y = fmaf(a.x, b.y, fmaf( a.y, b.x, acc.y));
  return acc; }
__device__ __forceinline__ float2 cmacc(float2 acc, float2 a, float2 b){ // acc += conj(a)*b
  acc.x = fmaf(a.x, b.x, fmaf( a.y, b.y, acc.x));
  acc.y = fmaf(a.x, b.y, fmaf(-a.y, b.x, acc.y));
  return acc; }
__device__ __forceinline__ float2 cdiv(float2 n, float2 d){
  float s = 1.0f / fmaf(d.x, d.x, d.y*d.y);
  return make_float2((n.x*d.x + n.y*d.y)*s, (n.y*d.x - n.x*d.y)*s); }

// Banded layout: band m = rows 16m..16m+15, row-stride 16(m+1) float2,
// rows zero-padded past the diagonal. offB(i,j) for j <= 16*(i/16)+15.
__device__ __forceinline__ int offB(int i, int j){
  const int m = i >> 4;
  return 128*m*(m+1) + ((i & 15) << 4)*(m+1) + j;
}

// Wilson-Dirac hop. EF = coefficient sign of G on the FORWARD hop:
//   D : fwd (I - G), bwd (I + G) -> EF=-1 ; Ddag : EF=+1
template<int EF>
__device__ __forceinline__ void dirac(const float2* __restrict__ U,
                                      const float2* __restrict__ vin,
                                      float2* __restrict__ vout, int t)
{
  if (t < NV) {
    const int s = t & 1, site = t >> 1;
    const int yi = site & 7, xi = site >> 3;
    const int xp = (xi+1)&7, xm = (xi-1)&7, yp = (yi+1)&7, ym = (yi-1)&7;
    float2 acc;
    {
      const int bf = (xp<<4) + (yi<<1);
      float2 fs = vin[bf + s], fo = vin[bf + (s^1)];
      float2 cf = (EF > 0) ? cadd(fs, fo) : csub(fs, fo);
      acc = cmul(U[(xi<<3)+yi], cf);
      const int bb = (xm<<4) + (yi<<1);
      float2 bs = vin[bb + s], bo = vin[bb + (s^1)];
      float2 cb = (EF > 0) ? csub(bs, bo) : cadd(bs, bo);
      acc = cadd(acc, cmulc(U[(xm<<3)+yi], cb));
    }
    {
      const float tg = s ? 1.0f : -1.0f;
      const float gf = (float)EF * tg;
      const int bf = (xi<<4) + (yp<<1);
      float2 fs = vin[bf + s], fo = vin[bf + (s^1)];
      float2 cf = make_float2(fmaf(-gf, fo.y, fs.x), fmaf(gf, fo.x, fs.y));
      acc = cadd(acc, cmul(U[64 + (xi<<3)+yi], cf));
      const float gb = -gf;
      const int bb = (xi<<4) + (ym<<1);
      float2 bs = vin[bb + s], bo = vin[bb + (s^1)];
      float2 cb = make_float2(fmaf(-gb, bo.y, bs.x), fmaf(gb, bo.x, bs.y));
      acc = cadd(acc, cmulc(U[64 + (xi<<3)+ym], cb));
    }
    float2 v0 = vin[t];
    vout[t] = make_float2(fmaf(-KAP, acc.x, v0.x), fmaf(-KAP, acc.y, v0.y));
  }
  __syncthreads();
}

// Octet-reduce (lanes differ in low 3 bits), result in all 8 lanes.
__device__ __forceinline__ float2 oct_reduce(float2 v){
  v.x += __shfl_xor(v.x, 1); v.y += __shfl_xor(v.y, 1);
  v.x += __shfl_xor(v.x, 2); v.y += __shfl_xor(v.y, 2);
  v.x += __shfl_xor(v.x, 4); v.y += __shfl_xor(v.y, 4);
  return v;
}

// z = L^H (L v).
// Pass 1 (L from banded LDS): octet (w,o) owns row-pair rS=8w+o, rL=127-rS
//   (lengths sum to 129 -> wave-uniform trips tS+tL = 9).
// Pass 2 (L^H from registers): same octet owns col-pair jL=8w+o, jS=127-jL;
//   LL = full col jL (8 slabs), LS = col jS (rows 64..127, 4 slabs),
//   above-diagonal entries zeroed at stage time. w[] reads are b128 broadcasts.
__device__ __forceinline__ void precond(const float2* __restrict__ Lc2,
                                        const float2 LL[8][2], const float2 LS[4][2],
                                        const float2* __restrict__ vin,
                                        float2* __restrict__ twv,
                                        float2* __restrict__ vout,
                                        int w, int oct, int cp)
{
  const int rS = (w << 3) + oct, rL = 127 - rS;
  const int jL = rS, jS = rL;
  // ---- pass 1 ----
  {
    const int tS = ((w << 3) + 23) >> 4;          // trips for short row (1..4), wave-uniform
    const int tL = (143 - (w << 3)) >> 4;         // trips for long row (5..8), wave-uniform
    const int mS = rS >> 4, mL = rL >> 4;
    const int baseS = 128*mS*(mS+1) + ((rS & 15) << 4)*(mS+1);
    const int baseL = 128*mL*(mL+1) + ((rL & 15) << 4)*(mL+1);
    float2 aS = f2(0.f,0.f), aL = f2(0.f,0.f);
    for (int k = 0; k < tS; ++k) {
      const int j0 = (k << 4) + (cp << 1);
      float4 Lp = *(const float4*)&Lc2[baseS + j0];
      float4 vp = *(const float4*)&vin[j0];
      aS = cmac(aS, f2(Lp.x, Lp.y), f2(vp.x, vp.y));
      aS = cmac(aS, f2(Lp.z, Lp.w), f2(vp.z, vp.w));
    }
    for (int k = 0; k < tL; ++k) {
      const int j0 = (k << 4) + (cp << 1);
      float4 Lp = *(const float4*)&Lc2[baseL + j0];
      float4 vp = *(const float4*)&vin[j0];
      aL = cmac(aL, f2(Lp.x, Lp.y), f2(vp.x, vp.y));
      aL = cmac(aL, f2(Lp.z, Lp.w), f2(vp.z, vp.w));
    }
    aS = oct_reduce(aS);
    aL = oct_reduce(aL);
    if (cp == 0) twv[rS] = aS;
    if (cp == 1) twv[rL] = aL;
  }
  __syncthreads();
  // ---- pass 2 ----
  {
    float2 aL2 = f2(0.f,0.f), aS2 = f2(0.f,0.f);
    #pragma unroll
    for (int k = 0; k < 8; ++k) {
      float4 wp = *(const float4*)&twv[(k << 4) + (cp << 1)];
      float2 w0 = f2(wp.x, wp.y), w1 = f2(wp.z, wp.w);
      aL2 = cmacc(aL2, LL[k][0], w0);
      aL2 = cmacc(aL2, LL[k][1], w1);
      if (k >= 4) {
        aS2 = cmacc(aS2, LS[k-4][0], w0);
        aS2 = cmacc(aS2, LS[k-4][1], w1);
      }
    }
    aL2 = oct_reduce(aL2);
    aS2 = oct_reduce(aS2);
    if (cp == 0) vout[jL] = aL2;
    if (cp == 1) vout[jS] = aS2;
  }
  __syncthreads();
}

// conj(a).c over t<128; scal slot double-buffered; internal barrier publishes.
__device__ __forceinline__ float2 block_dot(const float2* __restrict__ a, const float2* __restrict__ c,
                            float2* __restrict__ scal, int t, int slot)
{
  if (t < NV) {
    float2 v = cmacc(f2(0.f,0.f), a[t], c[t]);
    #pragma unroll
    for (int off = 32; off > 0; off >>= 1) {
      v.x += __shfl_down(v.x, off, 64);
      v.y += __shfl_down(v.y, off, 64);
    }
    if ((t & 63) == 0) scal[(slot<<1) + (t >> 6)] = v;
  }
  __syncthreads();
  return cadd(scal[slot<<1], scal[(slot<<1)+1]);
}

extern "C" __global__ void __launch_bounds__(TPB, 4)
cg_loss_kernel(const float* __restrict__ nre, const float* __restrict__ nim,
               const float* __restrict__ theta, const float* __restrict__ bin,
               float* __restrict__ out, float invB)
{
  __shared__ __align__(16) float2 Lc2[NB];          // 73728 B banded, zero-padded
  __shared__ __align__(16) float2 Uc[128];          // 1024 B
  __shared__ __align__(16) float2 rv[NV], pv[NV], zv[NV], Apv[NV], twv[NV]; // 5120 B
  __shared__ float2 scal[8];
  // total LDS = 73728 + 1024 + 5120 + 64 = 79936 B -> 2 blocks/CU

  const int t = threadIdx.x;
  const long long b = blockIdx.x;
  const int w = t >> 6, lane = t & 63, oct = lane >> 3, cp = lane & 7;

  // ---- zero the banded buffer (pads must be 0), then scatter-stage L ----
  {
    float4* L4 = (float4*)Lc2;
    for (int i = t; i < NB/2; i += TPB) L4[i] = make_float4(0.f,0.f,0.f,0.f);
  }
  __syncthreads();
  {
    const float* nreb = nre + b * NTRI;
    const float* nimb = nim + b * NTRI;
    for (int p = t; p < NTRI; p += TPB) {
      float re = nreb[p], im = nimb[p];
      int r = (int)((sqrtf(8.f * (float)p + 1.f) - 1.f) * 0.5f + 1e-3f);
      int tr = (r * (r + 1)) >> 1;
      if (tr > p)               { tr -= r; --r; }
      else if (tr + r + 1 <= p) { tr += r + 1; ++r; }
      Lc2[offB(r, p - tr)] = make_float2(re, im);
    }
  }
  float2 xr = f2(0.f, 0.f);                         // x[t] in register (t<128)
  if (t < NV) {
    float th = theta[b * 128 + t];
    float sn, cs;
    sincosf(th, &sn, &cs);
    Uc[t] = make_float2(cs, sn);                    // exp(i*theta)
    float bb = bin[b * 128 + t];
    rv[t] = make_float2(bb, 0.f);                   // r = b - A(0)
  }
  __syncthreads();

  // ---- stage pass-2 column-pair into registers (one-time) ----
  const int jL = (w << 3) + oct, jS = 127 - jL;
  float2 LL[8][2], LS[4][2];
  #pragma unroll
  for (int k = 0; k < 8; ++k) {
    const int i0 = (k << 4) + (cp << 1), i1 = i0 + 1;
    const int base = (128*k + 32*cp) * (k + 1);     // offB(i0, 0)
    float2 a = Lc2[base + jL];
    float2 c = Lc2[base + ((k + 1) << 4) + jL];     // offB(i1, jL)
    LL[k][0] = (i0 >= jL) ? a : f2(0.f,0.f);
    LL[k][1] = (i1 >= jL) ? c : f2(0.f,0.f);
    if (k >= 4) {
      float2 d = Lc2[base + jS];
      float2 e = Lc2[base + ((k + 1) << 4) + jS];
      LS[k-4][0] = (i0 >= jS) ? d : f2(0.f,0.f);
      LS[k-4][1] = (i1 >= jS) ? e : f2(0.f,0.f);
    }
  }

  precond(Lc2, LL, LS, rv, twv, zv, w, oct, cp);    // z = M r
  if (t < NV) pv[t] = zv[t];
  float2 rz = block_dot(rv, zv, scal, t, 0);        // internal barrier publishes pv

  #pragma unroll 1
  for (int it = 0; it < MAXIT; ++it) {
    dirac<-1>(Uc, pv, twv, t);                      // t1 = D p
    dirac<+1>(Uc, twv, Apv, t);                     // Ap = Ddag t1
    float2 pAp = block_dot(pv, Apv, scal, t, 1);
    if (t < NV) {
      float2 alpha = cdiv(rz, pAp);
      xr = cmac(xr, alpha, pv[t]);                  // x += alpha p (register)
      rv[t] = csub(rv[t], cmul(alpha, Apv[t]));     // r -= alpha Ap
    }
    __syncthreads();                                // rv visible to pass 1
    precond(Lc2, LL, LS, rv, twv, zv, w, oct, cp);  // z = M r
    float2 rz2 = block_dot(rv, zv, scal, t, 0);
    if (t < NV) {
      float2 beta = cdiv(rz2, rz);
      pv[t] = cmac(zv[t], beta, pv[t]);             // p = z + beta p
    }
    rz = rz2;
    __syncthreads();                                // pv visible to next dirac
  }

  // res = A x - b ; rn = ||res||
  if (t < NV) zv[t] = xr;
  __syncthreads();
  dirac<-1>(Uc, zv, twv, t);
  dirac<+1>(Uc, twv, Apv, t);
  if (t < NV) {
    float bb = bin[b * 128 + t];
    float2 d = csub(Apv[t], f2(bb, 0.f));
    float v = fmaf(d.x, d.x, d.y * d.y);
    #pragma unroll
    for (int off = 32; off > 0; off >>= 1) v += __shfl_down(v, off, 64);
    if ((t & 63) == 0) scal[4 + (t >> 6)].x = v;
  }
  __syncthreads();
  if (t == 0) {
    float rn = sqrtf(scal[4].x + scal[5].x);
    atomicAdd(out, rn * invB);
  }
}

extern "C" void kernel_launch(void* const* d_in, const int* in_sizes, int n_in,
                              void* d_out, int out_size, void* d_ws, size_t ws_size,
                              hipStream_t stream)
{
  const float* nre   = (const float*)d_in[0];
  const float* nim   = (const float*)d_in[1];
  const float* theta = (const float*)d_in[2];
  const float* bin   = (const float*)d_in[3];
  float* out = (float*)d_out;
  const int B = in_sizes[0] / NTRI;   // 2048

  hipMemsetAsync(out, 0, sizeof(float), stream);
  cg_loss_kernel<<<B, TPB, 0, stream>>>(nre, nim, theta, bin, out, 1.0f / (float)B);
}